// Round 2
// baseline (1238.531 us; speedup 1.0000x reference)
//
#include <hip/hip_runtime.h>
#include <hip/hip_bf16.h>
#include <stdint.h>

typedef short bhalf8 __attribute__((ext_vector_type(8)));
typedef float facc4 __attribute__((ext_vector_type(4)));

static __device__ __forceinline__ short f2bf(float f) {
  uint32_t u = __builtin_bit_cast(uint32_t, f);
  u = (u + 0x7FFFu + ((u >> 16) & 1u)) >> 16;  // RNE
  return (short)(uint16_t)u;
}

// ---------------------------------------------------------------------------
// prep: sample conv weights w = loc + L@eps (L = tril(-1)+softplus(diag)*I)
// bf16 layout wt[a=kh*3+kw][kc=i>>5][o][i&31]  (contiguous A-frag 1KB/wave),
// bias = bias_loc + eps_b*softplus(bias_ro), plus a 16-short zero pad used
// as the DMA source for SAME-padding halo lanes.
// ---------------------------------------------------------------------------
__global__ void prep_kernel(const float* __restrict__ wloc,
                            const float* __restrict__ wL,
                            const float* __restrict__ eps_w,
                            const float* __restrict__ bloc,
                            const float* __restrict__ bro,
                            const float* __restrict__ eps_b,
                            short* __restrict__ wt, float* __restrict__ bias,
                            short* __restrict__ zeros) {
  int t = blockIdx.x * 256 + threadIdx.x;  // t = o*64 + i
  int o = t >> 6, i = t & 63;
  int kc = i >> 5, il = i & 31;
  const float* Lp = wL + (size_t)t * 81;
  const float* ep = eps_w + (size_t)t * 9;
  const float* lp = wloc + (size_t)t * 9;
  float e[9];
#pragma unroll
  for (int b = 0; b < 9; ++b) e[b] = ep[b];
#pragma unroll
  for (int a = 0; a < 9; ++a) {
    float s = lp[a];
    for (int b = 0; b < a; ++b) s += Lp[a * 9 + b] * e[b];
    float d = Lp[a * 9 + a];
    float sp = (d > 20.f) ? d : log1pf(expf(d));
    s += sp * e[a];
    wt[((a * 2 + kc) * 64 + o) * 32 + il] = f2bf(s);
  }
  if (t < 64) {
    float d = bro[t];
    float sp = (d > 20.f) ? d : log1pf(expf(d));
    bias[t] = bloc[t] + eps_b[t] * sp;
  }
  if (t < 16) zeros[t] = 0;
}

// ---------------------------------------------------------------------------
// pass 1: x NCHW f32 -> NHWC bf16 (pixel-flattened [n][p][c64]).
// Thread: 4 consecutive pixels x 8 channels. 128B-segment loads, 128B stores.
// ---------------------------------------------------------------------------
__global__ __launch_bounds__(512) void to_nhwc_kernel(
    const float* __restrict__ x, short* __restrict__ xh) {
  int b = blockIdx.x;  // 32 n * 196 pixel-chunks of 256
  int n = b / 196;
  int p0 = (b % 196) * 256;
  int t = threadIdx.x;
  int pl = t >> 3, c8 = t & 7;
  const float* xp = x + (size_t)(n * 64 + c8 * 8) * 50176 + p0 + pl * 4;
  short* op = xh + ((size_t)n * 50176 + p0 + pl * 4) * 64 + c8 * 8;
  float4 v[8];
#pragma unroll
  for (int j = 0; j < 8; ++j) v[j] = *(const float4*)(xp + (size_t)j * 50176);
#pragma unroll
  for (int s = 0; s < 4; ++s) {
    bhalf8 h;
#pragma unroll
    for (int j = 0; j < 8; ++j) h[j] = f2bf(((const float*)&v[j])[s]);
    *(bhalf8*)(op + s * 64) = h;
  }
}

// ---------------------------------------------------------------------------
// pass 2: 3x3 SAME conv from NHWC bf16, 9 shifted K=32 GEMM steps x 2 rounds.
// Block: 64 o x (8 rows x 64 cols), 8 waves. LDS [10][66][32c] bf16 linear,
// staged via global_load_lds width-16 (halo lanes DMA from zero pad).
// B-frag ds_read_b128 is contiguous 1KB/wave -> bank-optimal, no swizzle.
// ---------------------------------------------------------------------------
__global__ __launch_bounds__(512, 6) void conv_nhwc_kernel(
    const short* __restrict__ xh, const short* __restrict__ wt,
    const float* __restrict__ bias, const short* __restrict__ zeros,
    float* __restrict__ out) {
  __shared__ short lds[10 * 66 * 32];  // 42240 B
  int b = blockIdx.x;
  int n = b / 112, rem = b % 112;
  int h0 = (rem >> 2) * 8, w0 = (rem & 3) * 64;
  int t = threadIdx.x, lane = t & 63, wv = t >> 6;
  int l15 = lane & 15, l4 = lane >> 4;

  facc4 acc[4][4];
#pragma unroll
  for (int om = 0; om < 4; ++om)
#pragma unroll
    for (int p = 0; p < 4; ++p) {
      facc4 z = {0.f, 0.f, 0.f, 0.f};
      acc[om][p] = z;
    }

  const size_t nbase = (size_t)n * 50176 * 64;
  for (int ic = 0; ic < 2; ++ic) {
    // ---- stage: 2640 16B chunks, id=(r*66+cc)*4+g, DMA direct to LDS ----
    for (int k = 0; k < 6; ++k) {
      int id = k * 512 + t;
      if (id < 2640) {
        int g = id & 3, pc = id >> 2;
        int cc = pc % 66, r = pc / 66;
        int h_in = h0 - 1 + r, w_in = w0 - 1 + cc;
        const short* src =
            (h_in >= 0 && h_in < 224 && w_in >= 0 && w_in < 224)
                ? xh + nbase + (size_t)(h_in * 224 + w_in) * 64 + ic * 32 + g * 8
                : zeros;
        __builtin_amdgcn_global_load_lds(
            (const __attribute__((address_space(1))) void*)src,
            (__attribute__((address_space(3))) void*)((char*)lds +
                                                      (k * 512 + wv * 64) * 16),
            16, 0, 0);
      }
    }
    __syncthreads();
    // ---- compute: 9 shifted positions, K=32 each ----
#pragma unroll
    for (int kh = 0; kh < 3; ++kh) {
      int r = wv + kh;
#pragma unroll
      for (int kw = 0; kw < 3; ++kw) {
        const short* wb =
            wt + (((kh * 3 + kw) * 2 + ic) * 64 + l15) * 32 + (l4 << 3);
        bhalf8 a[4];
#pragma unroll
        for (int om = 0; om < 4; ++om)
          a[om] = *(const bhalf8*)(wb + om * 16 * 32);
#pragma unroll
        for (int p = 0; p < 4; ++p) {
          int tc = p * 16 + l15 + kw;
          bhalf8 bbv = *(const bhalf8*)(lds + (r * 66 + tc) * 32 + (l4 << 3));
#pragma unroll
          for (int om = 0; om < 4; ++om)
            acc[om][p] = __builtin_amdgcn_mfma_f32_16x16x32_bf16(
                a[om], bbv, acc[om][p], 0, 0, 0);
        }
      }
    }
    __syncthreads();
  }

  // ---- epilogue: D[o=om*16+l4*4+j][px=p*16+l15] + bias, NCHW f32 out ----
  int h = h0 + wv;
#pragma unroll
  for (int om = 0; om < 4; ++om) {
#pragma unroll
    for (int j = 0; j < 4; ++j) {
      int o = om * 16 + l4 * 4 + j;
      float bo = bias[o];
      float* op = out + ((size_t)(n * 64 + o) * 224 + h) * 224 + w0;
#pragma unroll
      for (int p = 0; p < 4; ++p) {
        int wg = w0 + p * 16 + l15;
        if (wg < 224) op[p * 16 + l15] = acc[om][p][j] + bo;
      }
    }
  }
}

// ---------------------------------------------------------------------------
// fallback (ws too small): round-1 proven one-pass kernel, NCHW f32 staging
// with register transpose. Uses the same wt[a][kc][o][32] layout.
// ---------------------------------------------------------------------------
__global__ __launch_bounds__(512, 2) void conv_fallback_kernel(
    const float* __restrict__ x, const short* __restrict__ wt,
    const float* __restrict__ bias, float* __restrict__ out) {
  __shared__ short lds[10 * 66 * 32];
  int b = blockIdx.x;
  int n = b / 112, rem = b % 112;
  int h0 = (rem >> 2) * 8, w0 = (rem & 3) * 64;
  int t = threadIdx.x, lane = t & 63, wv = t >> 6;
  int l15 = lane & 15, l4 = lane >> 4;

  facc4 acc[4][4];
#pragma unroll
  for (int om = 0; om < 4; ++om)
#pragma unroll
    for (int p = 0; p < 4; ++p) {
      facc4 z = {0.f, 0.f, 0.f, 0.f};
      acc[om][p] = z;
    }

  for (int ic = 0; ic < 2; ++ic) {
    for (int k = 0; k < 6; ++k) {
      int id = t + k * 512;
      if (id < 2640) {
        int cc = id % 66;
        int rg = id / 66;
        int g = rg & 3, r = rg >> 2;
        int h_in = h0 - 1 + r, w_in = w0 - 1 + cc;
        bhalf8 v = {0, 0, 0, 0, 0, 0, 0, 0};
        if (h_in >= 0 && h_in < 224 && w_in >= 0 && w_in < 224) {
          const float* xp =
              x + ((size_t)((n * 64 + ic * 32 + g * 8) * 224 + h_in)) * 224 +
              w_in;
#pragma unroll
          for (int j = 0; j < 8; ++j) v[j] = f2bf(xp[(size_t)j * 50176]);
        }
        *(bhalf8*)(lds + (r * 66 + cc) * 32 + ((g ^ ((cc >> 1) & 3)) << 3)) = v;
      }
    }
    __syncthreads();
#pragma unroll
    for (int kh = 0; kh < 3; ++kh) {
      int r = wv + kh;
#pragma unroll
      for (int kw = 0; kw < 3; ++kw) {
        const short* wb =
            wt + (((kh * 3 + kw) * 2 + ic) * 64 + l15) * 32 + (l4 << 3);
        bhalf8 a[4], bb[4];
#pragma unroll
        for (int om = 0; om < 4; ++om)
          a[om] = *(const bhalf8*)(wb + om * 16 * 32);
#pragma unroll
        for (int p = 0; p < 4; ++p) {
          int tc = p * 16 + l15 + kw;
          bb[p] = *(const bhalf8*)(lds + (r * 66 + tc) * 32 +
                                   ((l4 ^ ((tc >> 1) & 3)) << 3));
        }
#pragma unroll
        for (int om = 0; om < 4; ++om)
#pragma unroll
          for (int p = 0; p < 4; ++p)
            acc[om][p] = __builtin_amdgcn_mfma_f32_16x16x32_bf16(
                a[om], bb[p], acc[om][p], 0, 0, 0);
      }
    }
    __syncthreads();
  }

  int h = h0 + wv;
#pragma unroll
  for (int om = 0; om < 4; ++om) {
#pragma unroll
    for (int j = 0; j < 4; ++j) {
      int o = om * 16 + l4 * 4 + j;
      float bo = bias[o];
      float* op = out + ((size_t)(n * 64 + o) * 224 + h) * 224 + w0;
#pragma unroll
      for (int p = 0; p < 4; ++p) {
        int wg = w0 + p * 16 + l15;
        if (wg < 224) op[p * 16 + l15] = acc[om][p][j] + bo;
      }
    }
  }
}

extern "C" void kernel_launch(void* const* d_in, const int* in_sizes, int n_in,
                              void* d_out, int out_size, void* d_ws,
                              size_t ws_size, hipStream_t stream) {
  const float* x = (const float*)d_in[0];
  const float* wloc = (const float*)d_in[1];
  const float* wL = (const float*)d_in[2];
  const float* bloc = (const float*)d_in[3];
  const float* bro = (const float*)d_in[4];
  const float* eps_w = (const float*)d_in[5];
  const float* eps_b = (const float*)d_in[6];
  float* outp = (float*)d_out;

  short* wt = (short*)d_ws;                      // 9*2*64*32 bf16 = 73728 B
  float* bias = (float*)((char*)d_ws + 73728);   // 64 f32 (256 B slot)
  short* zeros = (short*)((char*)d_ws + 73984);  // 16 bf16 zero pad (256 B)
  short* xh = (short*)((char*)d_ws + 74240);     // 32*50176*64 bf16 = 205.5 MB
  const size_t need = 74240ull + (size_t)32 * 50176 * 64 * 2;

  prep_kernel<<<16, 256, 0, stream>>>(wloc, wL, eps_w, bloc, bro, eps_b, wt,
                                      bias, zeros);
  if (ws_size >= need) {
    to_nhwc_kernel<<<32 * 196, 512, 0, stream>>>(x, xh);
    conv_nhwc_kernel<<<3584, 512, 0, stream>>>(xh, wt, bias, zeros, outp);
  } else {
    conv_fallback_kernel<<<3584, 512, 0, stream>>>(x, wt, bias, outp);
  }
}

// Round 3
// 581.979 us; speedup vs baseline: 2.1281x; 2.1281x over previous
//
#include <hip/hip_runtime.h>
#include <hip/hip_bf16.h>
#include <stdint.h>

typedef short bhalf8 __attribute__((ext_vector_type(8)));
typedef float facc4 __attribute__((ext_vector_type(4)));

static __device__ __forceinline__ short f2bf(float f) {
  uint32_t u = __builtin_bit_cast(uint32_t, f);
  u = (u + 0x7FFFu + ((u >> 16) & 1u)) >> 16;  // RNE
  return (short)(uint16_t)u;
}

// ---------------------------------------------------------------------------
// prep: sample conv weights w = loc + L@eps (L = tril(-1)+softplus(diag)*I)
// bf16 layout wt[a=kh*3+kw][kc=i>>5][o][i&31] (A-frag = contiguous 1KB/wave),
// bias = bias_loc + eps_b*softplus(bias_ro), 16-short zero pad for w-halo.
// ---------------------------------------------------------------------------
__global__ void prep_kernel(const float* __restrict__ wloc,
                            const float* __restrict__ wL,
                            const float* __restrict__ eps_w,
                            const float* __restrict__ bloc,
                            const float* __restrict__ bro,
                            const float* __restrict__ eps_b,
                            short* __restrict__ wt, float* __restrict__ bias,
                            short* __restrict__ zeros) {
  int t = blockIdx.x * 256 + threadIdx.x;  // t = o*64 + i
  int o = t >> 6, i = t & 63;
  int kc = i >> 5, il = i & 31;
  const float* Lp = wL + (size_t)t * 81;
  const float* ep = eps_w + (size_t)t * 9;
  const float* lp = wloc + (size_t)t * 9;
  float e[9];
#pragma unroll
  for (int b = 0; b < 9; ++b) e[b] = ep[b];
#pragma unroll
  for (int a = 0; a < 9; ++a) {
    float s = lp[a];
    for (int b = 0; b < a; ++b) s += Lp[a * 9 + b] * e[b];
    float d = Lp[a * 9 + a];
    float sp = (d > 20.f) ? d : log1pf(expf(d));
    s += sp * e[a];
    wt[((a * 2 + kc) * 64 + o) * 32 + il] = f2bf(s);
  }
  if (t < 64) {
    float d = bro[t];
    float sp = (d > 20.f) ? d : log1pf(expf(d));
    bias[t] = bloc[t] + eps_b[t] * sp;
  }
  if (t < 16) zeros[t] = 0;
}

// ---------------------------------------------------------------------------
// pass 1: x NCHW f32 -> NHWC bf16 ([n][p=h*224+w][c64]).
// Thread: 4 consecutive pixels x 8 channels; 128B-coalesced loads & stores.
// ---------------------------------------------------------------------------
__global__ __launch_bounds__(512) void to_nhwc_kernel(
    const float* __restrict__ x, short* __restrict__ xh) {
  int b = blockIdx.x;  // 32 n * 196 pixel-chunks of 256
  int n = b / 196;
  int p0 = (b % 196) * 256;
  int t = threadIdx.x;
  int pl = t >> 3, c8 = t & 7;
  const float* xp = x + (size_t)(n * 64 + c8 * 8) * 50176 + p0 + pl * 4;
  short* op = xh + ((size_t)n * 50176 + p0 + pl * 4) * 64 + c8 * 8;
  float4 v[8];
#pragma unroll
  for (int j = 0; j < 8; ++j) v[j] = *(const float4*)(xp + (size_t)j * 50176);
#pragma unroll
  for (int s = 0; s < 4; ++s) {
    bhalf8 h;
#pragma unroll
    for (int j = 0; j < 8; ++j) h[j] = f2bf(((const float*)&v[j])[s]);
    *(bhalf8*)(op + s * 64) = h;
  }
}

// ---------------------------------------------------------------------------
// pass 2: 3x3 SAME conv, NO LDS: B-frags loaded straight from NHWC bf16
// (tile working set ~84 KB -> L1/L2-hot; taps re-read cached lines).
// Block = 4 waves; wave = 1 output row x 64 px x 64 o (4x4 16x16 frags).
// h-halo: wave-uniform skip (B=0 contributes 0). w-halo: zero-buffer select.
// XCD-chunked blockIdx swizzle for vertical halo L2 reuse (7168 % 8 == 0).
// ---------------------------------------------------------------------------
__global__ __launch_bounds__(256, 4) void conv_direct_kernel(
    const short* __restrict__ xh, const short* __restrict__ wt,
    const float* __restrict__ bias, const short* __restrict__ zeros,
    float* __restrict__ out) {
  int b0 = blockIdx.x;
  int b = (b0 & 7) * (7168 >> 3) + (b0 >> 3);  // bijective: 7168 % 8 == 0
  int n = b / 224, rem = b % 224;
  int rq = rem % 56, w4 = rem / 56;  // consecutive b = vertical neighbors
  int h0 = rq * 4, w0 = w4 * 64;
  int t = threadIdx.x, lane = t & 63, wv = t >> 6;
  int l15 = lane & 15, l4 = lane >> 4;
  int h = h0 + wv;

  facc4 acc[4][4];
#pragma unroll
  for (int om = 0; om < 4; ++om)
#pragma unroll
    for (int p = 0; p < 4; ++p) {
      facc4 z = {0.f, 0.f, 0.f, 0.f};
      acc[om][p] = z;
    }

  const size_t nbase = (size_t)n * 50176 * 64;
  for (int ic = 0; ic < 2; ++ic) {
#pragma unroll
    for (int kh = 0; kh < 3; ++kh) {
      int hin = h + kh - 1;
      if (hin < 0 || hin >= 224) continue;  // wave-uniform
      const short* rowp =
          xh + nbase + (size_t)hin * 224 * 64 + ic * 32 + (l4 << 3);
#pragma unroll
      for (int kw = 0; kw < 3; ++kw) {
        const short* wb =
            wt + (((kh * 3 + kw) * 2 + ic) * 64 + l15) * 32 + (l4 << 3);
        bhalf8 a[4];
#pragma unroll
        for (int om = 0; om < 4; ++om)
          a[om] = *(const bhalf8*)(wb + om * 512);
#pragma unroll
        for (int p = 0; p < 4; ++p) {
          int pw = w0 + p * 16 + l15 + kw - 1;
          const short* src =
              (pw >= 0 && pw < 224) ? rowp + (size_t)pw * 64 : zeros;
          bhalf8 bv = *(const bhalf8*)src;
#pragma unroll
          for (int om = 0; om < 4; ++om)
            acc[om][p] = __builtin_amdgcn_mfma_f32_16x16x32_bf16(
                a[om], bv, acc[om][p], 0, 0, 0);
        }
      }
    }
  }

  // ---- epilogue: D[o=om*16+l4*4+j][px=p*16+l15] + bias, NCHW f32 out ----
#pragma unroll
  for (int om = 0; om < 4; ++om) {
#pragma unroll
    for (int j = 0; j < 4; ++j) {
      int o = om * 16 + l4 * 4 + j;
      float bo = bias[o];
      float* op = out + ((size_t)(n * 64 + o) * 224 + h) * 224 + w0;
#pragma unroll
      for (int p = 0; p < 4; ++p) {
        int wg = w0 + p * 16 + l15;
        if (wg < 224) op[p * 16 + l15] = acc[om][p][j] + bo;
      }
    }
  }
}

// ---------------------------------------------------------------------------
// fallback (ws too small): round-1 proven one-pass kernel (519 us).
// ---------------------------------------------------------------------------
__global__ __launch_bounds__(512, 2) void conv_fallback_kernel(
    const float* __restrict__ x, const short* __restrict__ wt,
    const float* __restrict__ bias, float* __restrict__ out) {
  __shared__ short lds[10 * 66 * 32];
  int b = blockIdx.x;
  int n = b / 112, rem = b % 112;
  int h0 = (rem >> 2) * 8, w0 = (rem & 3) * 64;
  int t = threadIdx.x, lane = t & 63, wv = t >> 6;
  int l15 = lane & 15, l4 = lane >> 4;

  facc4 acc[4][4];
#pragma unroll
  for (int om = 0; om < 4; ++om)
#pragma unroll
    for (int p = 0; p < 4; ++p) {
      facc4 z = {0.f, 0.f, 0.f, 0.f};
      acc[om][p] = z;
    }

  for (int ic = 0; ic < 2; ++ic) {
    for (int k = 0; k < 6; ++k) {
      int id = t + k * 512;
      if (id < 2640) {
        int cc = id % 66;
        int rg = id / 66;
        int g = rg & 3, r = rg >> 2;
        int h_in = h0 - 1 + r, w_in = w0 - 1 + cc;
        bhalf8 v = {0, 0, 0, 0, 0, 0, 0, 0};
        if (h_in >= 0 && h_in < 224 && w_in >= 0 && w_in < 224) {
          const float* xp =
              x + ((size_t)((n * 64 + ic * 32 + g * 8) * 224 + h_in)) * 224 +
              w_in;
#pragma unroll
          for (int j = 0; j < 8; ++j) v[j] = f2bf(xp[(size_t)j * 50176]);
        }
        *(bhalf8*)(lds + (r * 66 + cc) * 32 + ((g ^ ((cc >> 1) & 3)) << 3)) = v;
      }
    }
    __syncthreads();
#pragma unroll
    for (int kh = 0; kh < 3; ++kh) {
      int r = wv + kh;
#pragma unroll
      for (int kw = 0; kw < 3; ++kw) {
        const short* wb =
            wt + (((kh * 3 + kw) * 2 + ic) * 64 + l15) * 32 + (l4 << 3);
        bhalf8 a[4], bb[4];
#pragma unroll
        for (int om = 0; om < 4; ++om)
          a[om] = *(const bhalf8*)(wb + om * 16 * 32);
#pragma unroll
        for (int p = 0; p < 4; ++p) {
          int tc = p * 16 + l15 + kw;
          bb[p] = *(const bhalf8*)(lds + (r * 66 + tc) * 32 +
                                   ((l4 ^ ((tc >> 1) & 3)) << 3));
        }
#pragma unroll
        for (int om = 0; om < 4; ++om)
#pragma unroll
          for (int p = 0; p < 4; ++p)
            acc[om][p] = __builtin_amdgcn_mfma_f32_16x16x32_bf16(
                a[om], bb[p], acc[om][p], 0, 0, 0);
      }
    }
    __syncthreads();
  }

  int h = h0 + wv;
#pragma unroll
  for (int om = 0; om < 4; ++om) {
#pragma unroll
    for (int j = 0; j < 4; ++j) {
      int o = om * 16 + l4 * 4 + j;
      float bo = bias[o];
      float* op = out + ((size_t)(n * 64 + o) * 224 + h) * 224 + w0;
#pragma unroll
      for (int p = 0; p < 4; ++p) {
        int wg = w0 + p * 16 + l15;
        if (wg < 224) op[p * 16 + l15] = acc[om][p][j] + bo;
      }
    }
  }
}

extern "C" void kernel_launch(void* const* d_in, const int* in_sizes, int n_in,
                              void* d_out, int out_size, void* d_ws,
                              size_t ws_size, hipStream_t stream) {
  const float* x = (const float*)d_in[0];
  const float* wloc = (const float*)d_in[1];
  const float* wL = (const float*)d_in[2];
  const float* bloc = (const float*)d_in[3];
  const float* bro = (const float*)d_in[4];
  const float* eps_w = (const float*)d_in[5];
  const float* eps_b = (const float*)d_in[6];
  float* outp = (float*)d_out;

  short* wt = (short*)d_ws;                      // 9*2*64*32 bf16 = 73728 B
  float* bias = (float*)((char*)d_ws + 73728);   // 64 f32 (256 B slot)
  short* zeros = (short*)((char*)d_ws + 73984);  // 16 bf16 zero pad (256 B)
  short* xh = (short*)((char*)d_ws + 74240);     // 32*50176*64 bf16 = 205.5 MB
  const size_t need = 74240ull + (size_t)32 * 50176 * 64 * 2;

  prep_kernel<<<16, 256, 0, stream>>>(wloc, wL, eps_w, bloc, bro, eps_b, wt,
                                      bias, zeros);
  if (ws_size >= need) {
    to_nhwc_kernel<<<32 * 196, 512, 0, stream>>>(x, xh);
    conv_direct_kernel<<<7168, 256, 0, stream>>>(xh, wt, bias, zeros, outp);
  } else {
    conv_fallback_kernel<<<3584, 512, 0, stream>>>(x, wt, bias, outp);
  }
}

// Round 4
// 468.538 us; speedup vs baseline: 2.6434x; 1.2421x over previous
//
#include <hip/hip_runtime.h>
#include <hip/hip_bf16.h>
#include <stdint.h>

typedef short bhalf8 __attribute__((ext_vector_type(8)));
typedef float facc4 __attribute__((ext_vector_type(4)));
typedef unsigned int uintv2 __attribute__((ext_vector_type(2)));

static __device__ __forceinline__ unsigned short f2bfu(float f) {
  // hardware bf16 convert (RNE) — compiler emits v_cvt_*_bf16 on gfx950
  return __builtin_bit_cast(unsigned short, __float2bfloat16(f));
}

// ---------------------------------------------------------------------------
// prep: sample conv weights w = loc + L@eps (L = tril(-1)+softplus(diag)*I)
// bf16 layout wt[a=kh*3+kw][kc=i>>5][o][i&31] (A-frag = contiguous 1KB/wave),
// bias = bias_loc + eps_b*softplus(bias_ro).
// ---------------------------------------------------------------------------
__global__ void prep_kernel(const float* __restrict__ wloc,
                            const float* __restrict__ wL,
                            const float* __restrict__ eps_w,
                            const float* __restrict__ bloc,
                            const float* __restrict__ bro,
                            const float* __restrict__ eps_b,
                            short* __restrict__ wt, float* __restrict__ bias) {
  int t = blockIdx.x * 256 + threadIdx.x;  // t = o*64 + i
  int o = t >> 6, i = t & 63;
  int kc = i >> 5, il = i & 31;
  const float* Lp = wL + (size_t)t * 81;
  const float* ep = eps_w + (size_t)t * 9;
  const float* lp = wloc + (size_t)t * 9;
  float e[9];
#pragma unroll
  for (int b = 0; b < 9; ++b) e[b] = ep[b];
#pragma unroll
  for (int a = 0; a < 9; ++a) {
    float s = lp[a];
    for (int b = 0; b < a; ++b) s += Lp[a * 9 + b] * e[b];
    float d = Lp[a * 9 + a];
    float sp = (d > 20.f) ? d : log1pf(expf(d));
    s += sp * e[a];
    wt[((a * 2 + kc) * 64 + o) * 32 + il] = (short)f2bfu(s);
  }
  if (t < 64) {
    float d = bro[t];
    float sp = (d > 20.f) ? d : log1pf(expf(d));
    bias[t] = bloc[t] + eps_b[t] * sp;
  }
}

// ---------------------------------------------------------------------------
// one-pass 3x3 SAME conv. Block = 8 waves, out-tile 64o x (8 rows x 64 px).
// Per ic-round (32 ch): stage x fp32 NCHW -> LDS bf16 [10 r][66 cc][32 ch]
// (float4 loads, 4px x 4ch register transpose, hw cvt, b64 writes, 16B-granule
// XOR swizzle g^=((cc>>1)&3) — R1-proven ~0 bank conflicts). Then 9 shifted
// K=32 GEMM steps: A-frags (1KB/wave, L1-hot) from global wt, B-frags
// ds_read_b128. acc in AGPRs (64) + VGPR<=64 -> 2 blocks/CU (16 waves).
// Block order: consecutive blocks = vertically adjacent tiles, XCD-chunked
// so halo rows hit the same XCD's L2.
// ---------------------------------------------------------------------------
__global__ __launch_bounds__(512, 4) void conv_onepass_kernel(
    const float* __restrict__ x, const short* __restrict__ wt,
    const float* __restrict__ bias, float* __restrict__ out) {
  __shared__ short lds[10 * 66 * 32];  // 42240 B
  int b0 = blockIdx.x;
  int b = (b0 & 7) * 448 + (b0 >> 3);  // bijective: 3584 % 8 == 0
  int ht = b % 28;
  int rest = b / 28;
  int w4 = rest & 3, n = rest >> 2;
  int h0 = ht * 8, w0 = w4 * 64;
  int t = threadIdx.x, lane = t & 63, wv = t >> 6;
  int l15 = lane & 15, l4 = lane >> 4;

  facc4 acc[4][4];
#pragma unroll
  for (int om = 0; om < 4; ++om)
#pragma unroll
    for (int p = 0; p < 4; ++p) {
      facc4 z = {0.f, 0.f, 0.f, 0.f};
      acc[om][p] = z;
    }

  for (int ic = 0; ic < 2; ++ic) {
    // ---- stage: units = r(10) x ccg(17, 4px) x chg(8, 4ch) = 1360 ----
#pragma unroll
    for (int k = 0; k < 3; ++k) {
      int u = t + k * 512;
      if (u < 1360) {
        int chg = u & 7;
        int tmp = u >> 3;
        int ccg = tmp % 17, r = tmp / 17;
        int h_in = h0 - 1 + r;
        bool hok = (h_in >= 0) & (h_in < 224);
        int w_in0 = w0 - 1 + ccg * 4;
        int ch0 = ic * 32 + chg * 4;
        const float* cbase =
            x + ((size_t)(n * 64 + ch0) * 224 + (hok ? h_in : 0)) * 224;
        float4 v[4];
        if (hok && w_in0 >= 0 && w_in0 + 3 < 224) {
#pragma unroll
          for (int cj = 0; cj < 4; ++cj)
            v[cj] = *(const float4*)(cbase + (size_t)cj * 50176 + w_in0);
        } else {
#pragma unroll
          for (int cj = 0; cj < 4; ++cj) {
            float* vf = (float*)&v[cj];
#pragma unroll
            for (int i = 0; i < 4; ++i) {
              int w_in = w_in0 + i;
              bool ok = hok & (w_in >= 0) & (w_in < 224);
              vf[i] = ok ? cbase[(size_t)cj * 50176 + w_in] : 0.f;
            }
          }
        }
        // transpose 4px x 4ch -> per-px packed bf16 pair, b64 LDS write
#pragma unroll
        for (int i = 0; i < 4; ++i) {
          int cc = ccg * 4 + i;
          if (cc < 66) {
            const float* v0 = (const float*)&v[0];
            const float* v1 = (const float*)&v[1];
            const float* v2 = (const float*)&v[2];
            const float* v3 = (const float*)&v[3];
            unsigned int w0p =
                (unsigned int)f2bfu(v0[i]) | ((unsigned int)f2bfu(v1[i]) << 16);
            unsigned int w1p =
                (unsigned int)f2bfu(v2[i]) | ((unsigned int)f2bfu(v3[i]) << 16);
            int g = chg >> 1;
            int addr = (r * 66 + cc) * 32 + ((g ^ ((cc >> 1) & 3)) << 3) +
                       ((chg & 1) << 2);
            uintv2 pk = {w0p, w1p};
            *(uintv2*)(lds + addr) = pk;
          }
        }
      }
    }
    __syncthreads();
    // ---- compute: 9 shifted positions, K=32 each ----
#pragma unroll
    for (int kh = 0; kh < 3; ++kh) {
      int r = wv + kh;  // input tile row for this wave's out row
#pragma unroll
      for (int kw = 0; kw < 3; ++kw) {
        const short* wb =
            wt + (((kh * 3 + kw) * 2 + ic) * 64 + l15) * 32 + (l4 << 3);
        bhalf8 a[4];
#pragma unroll
        for (int om = 0; om < 4; ++om)
          a[om] = *(const bhalf8*)(wb + om * 512);
#pragma unroll
        for (int p = 0; p < 4; ++p) {
          int tc = p * 16 + l15 + kw;
          bhalf8 bv = *(const bhalf8*)(lds + (r * 66 + tc) * 32 +
                                       ((l4 ^ ((tc >> 1) & 3)) << 3));
#pragma unroll
          for (int om = 0; om < 4; ++om)
            acc[om][p] = __builtin_amdgcn_mfma_f32_16x16x32_bf16(
                a[om], bv, acc[om][p], 0, 0, 0);
        }
      }
    }
    __syncthreads();
  }

  // ---- epilogue: D[o=om*16+l4*4+j][px=p*16+l15] + bias, NCHW f32 out ----
  int h = h0 + wv;
#pragma unroll
  for (int om = 0; om < 4; ++om) {
#pragma unroll
    for (int j = 0; j < 4; ++j) {
      int o = om * 16 + l4 * 4 + j;
      float bo = bias[o];
      float* op = out + ((size_t)(n * 64 + o) * 224 + h) * 224 + w0;
#pragma unroll
      for (int p = 0; p < 4; ++p) {
        int wg = w0 + p * 16 + l15;
        if (wg < 224) op[p * 16 + l15] = acc[om][p][j] + bo;
      }
    }
  }
}

extern "C" void kernel_launch(void* const* d_in, const int* in_sizes, int n_in,
                              void* d_out, int out_size, void* d_ws,
                              size_t ws_size, hipStream_t stream) {
  const float* x = (const float*)d_in[0];
  const float* wloc = (const float*)d_in[1];
  const float* wL = (const float*)d_in[2];
  const float* bloc = (const float*)d_in[3];
  const float* bro = (const float*)d_in[4];
  const float* eps_w = (const float*)d_in[5];
  const float* eps_b = (const float*)d_in[6];
  float* outp = (float*)d_out;

  short* wt = (short*)d_ws;                     // 9*2*64*32 bf16 = 73728 B
  float* bias = (float*)((char*)d_ws + 73728);  // 64 f32

  prep_kernel<<<16, 256, 0, stream>>>(wloc, wL, eps_w, bloc, bro, eps_b, wt,
                                      bias);
  conv_onepass_kernel<<<3584, 512, 0, stream>>>(x, wt, bias, outp);
}

// Round 5
// 460.452 us; speedup vs baseline: 2.6898x; 1.0176x over previous
//
#include <hip/hip_runtime.h>
#include <hip/hip_bf16.h>
#include <stdint.h>

typedef short bhalf8 __attribute__((ext_vector_type(8)));
typedef float facc4 __attribute__((ext_vector_type(4)));
typedef unsigned int uintv2 __attribute__((ext_vector_type(2)));

static __device__ __forceinline__ unsigned short f2bfu(float f) {
  return __builtin_bit_cast(unsigned short, __float2bfloat16(f));
}

// ---------------------------------------------------------------------------
// prep: sample conv weights w = loc + L@eps (L = tril(-1)+softplus(diag)*I)
// bf16 layout wt[a=kh*3+kw][kc=i>>5][o][i&31] (A-frag = contiguous 1KB/wave),
// bias = bias_loc + eps_b*softplus(bias_ro).
// ---------------------------------------------------------------------------
__global__ void prep_kernel(const float* __restrict__ wloc,
                            const float* __restrict__ wL,
                            const float* __restrict__ eps_w,
                            const float* __restrict__ bloc,
                            const float* __restrict__ bro,
                            const float* __restrict__ eps_b,
                            short* __restrict__ wt, float* __restrict__ bias) {
  int t = blockIdx.x * 256 + threadIdx.x;  // t = o*64 + i
  int o = t >> 6, i = t & 63;
  int kc = i >> 5, il = i & 31;
  const float* Lp = wL + (size_t)t * 81;
  const float* ep = eps_w + (size_t)t * 9;
  const float* lp = wloc + (size_t)t * 9;
  float e[9];
#pragma unroll
  for (int b = 0; b < 9; ++b) e[b] = ep[b];
#pragma unroll
  for (int a = 0; a < 9; ++a) {
    float s = lp[a];
    for (int b = 0; b < a; ++b) s += Lp[a * 9 + b] * e[b];
    float d = Lp[a * 9 + a];
    float sp = (d > 20.f) ? d : log1pf(expf(d));
    s += sp * e[a];
    wt[((a * 2 + kc) * 64 + o) * 32 + il] = (short)f2bfu(s);
  }
  if (t < 64) {
    float d = bro[t];
    float sp = (d > 20.f) ? d : log1pf(expf(d));
    bias[t] = bloc[t] + eps_b[t] * sp;
  }
}

// ---------------------------------------------------------------------------
// one-pass 3x3 SAME conv. Block = 4 waves (256 thr), out-tile 64o x 4r x 64px.
// LDS [6 r][66 cc][32 ch] bf16 = 25.3 KB -> 4 blocks/CU (16 waves): phase
// overlap across blocks (one stages while three compute). Staging: float4
// loads, 4px x 4ch register transpose (named regs, no arrays), hw bf16 cvt,
// b64 writes with R1-proven 16B-granule XOR swizzle. Compute: 9 shifted
// K=32 GEMM steps, A-frags (1KB/wave) global L1-hot, B-frags ds_read_b128.
// Block order: vertical-adjacent consecutive + XCD chunk (halo-row L2 reuse).
// ---------------------------------------------------------------------------
#define LD1(cj, i)                                                   \
  ((hok && (w_in0 + (i)) >= 0 && (w_in0 + (i)) < 224)                \
       ? cbase[(size_t)(cj) * 50176 + w_in0 + (i)]                   \
       : 0.f)

__global__ __launch_bounds__(256, 4) void conv_onepass_kernel(
    const float* __restrict__ x, const short* __restrict__ wt,
    const float* __restrict__ bias, float* __restrict__ out) {
  __shared__ short lds[6 * 66 * 32];  // 25344 B
  int b0 = blockIdx.x;
  int b = (b0 & 7) * 896 + (b0 >> 3);  // bijective: 7168 % 8 == 0
  int ht = b % 56;
  int rest = b / 56;
  int w4 = rest & 3, n = rest >> 2;
  int h0 = ht * 4, w0 = w4 * 64;
  int t = threadIdx.x, lane = t & 63, wv = t >> 6;
  int l15 = lane & 15, l4 = lane >> 4;

  facc4 acc[4][4];
#pragma unroll
  for (int om = 0; om < 4; ++om)
#pragma unroll
    for (int p = 0; p < 4; ++p) {
      facc4 z = {0.f, 0.f, 0.f, 0.f};
      acc[om][p] = z;
    }

  for (int ic = 0; ic < 2; ++ic) {
    // ---- stage: units = r(6) x ccg(17, 4px) x chg(8, 4ch) = 816 ----
#pragma unroll
    for (int k = 0; k < 4; ++k) {
      int u = t + k * 256;
      if (u < 816) {
        int chg = u & 7;
        int tmp = u >> 3;
        int ccg = tmp % 17, r = tmp / 17;
        int h_in = h0 - 1 + r;
        bool hok = (h_in >= 0) & (h_in < 224);
        int w_in0 = w0 - 1 + ccg * 4;
        int ch0 = ic * 32 + chg * 4;
        const float* cbase =
            x + ((size_t)(n * 64 + ch0) * 224 + (hok ? h_in : 0)) * 224;
        float4 v0, v1, v2, v3;
        if (hok && w_in0 >= 0 && w_in0 + 3 < 224) {
          v0 = *(const float4*)(cbase + w_in0);
          v1 = *(const float4*)(cbase + 50176 + w_in0);
          v2 = *(const float4*)(cbase + 2 * 50176 + w_in0);
          v3 = *(const float4*)(cbase + 3 * 50176 + w_in0);
        } else {
          v0 = make_float4(LD1(0, 0), LD1(0, 1), LD1(0, 2), LD1(0, 3));
          v1 = make_float4(LD1(1, 0), LD1(1, 1), LD1(1, 2), LD1(1, 3));
          v2 = make_float4(LD1(2, 0), LD1(2, 1), LD1(2, 2), LD1(2, 3));
          v3 = make_float4(LD1(3, 0), LD1(3, 1), LD1(3, 2), LD1(3, 3));
        }
        int g = chg >> 1;
        int halfsel = (chg & 1) << 2;
#pragma unroll
        for (int i = 0; i < 4; ++i) {
          int cc = ccg * 4 + i;
          if (cc < 66) {
            float a0 = ((const float*)&v0)[i], a1 = ((const float*)&v1)[i];
            float a2 = ((const float*)&v2)[i], a3 = ((const float*)&v3)[i];
            unsigned int w0p =
                (unsigned int)f2bfu(a0) | ((unsigned int)f2bfu(a1) << 16);
            unsigned int w1p =
                (unsigned int)f2bfu(a2) | ((unsigned int)f2bfu(a3) << 16);
            int addr = (r * 66 + cc) * 32 + ((g ^ ((cc >> 1) & 3)) << 3) +
                       halfsel;
            uintv2 pk = {w0p, w1p};
            *(uintv2*)(lds + addr) = pk;
          }
        }
      }
    }
    __syncthreads();
    // ---- compute: 9 shifted positions, K=32 each ----
#pragma unroll
    for (int kh = 0; kh < 3; ++kh) {
      int r = wv + kh;  // input tile row for this wave's out row
#pragma unroll
      for (int kw = 0; kw < 3; ++kw) {
        const short* wb =
            wt + (((kh * 3 + kw) * 2 + ic) * 64 + l15) * 32 + (l4 << 3);
        bhalf8 a[4];
#pragma unroll
        for (int om = 0; om < 4; ++om)
          a[om] = *(const bhalf8*)(wb + om * 512);
#pragma unroll
        for (int p = 0; p < 4; ++p) {
          int tc = p * 16 + l15 + kw;
          bhalf8 bv = *(const bhalf8*)(lds + (r * 66 + tc) * 32 +
                                       ((l4 ^ ((tc >> 1) & 3)) << 3));
#pragma unroll
          for (int om = 0; om < 4; ++om)
            acc[om][p] = __builtin_amdgcn_mfma_f32_16x16x32_bf16(
                a[om], bv, acc[om][p], 0, 0, 0);
        }
      }
    }
    if (ic == 0) __syncthreads();
  }

  // ---- epilogue: D[o=om*16+l4*4+j][px=p*16+l15] + bias, NCHW f32 out ----
  int h = h0 + wv;
#pragma unroll
  for (int om = 0; om < 4; ++om) {
#pragma unroll
    for (int j = 0; j < 4; ++j) {
      int o = om * 16 + l4 * 4 + j;
      float bo = bias[o];
      float* op = out + ((size_t)(n * 64 + o) * 224 + h) * 224 + w0;
#pragma unroll
      for (int p = 0; p < 4; ++p) {
        int wg = w0 + p * 16 + l15;
        if (wg < 224) op[p * 16 + l15] = acc[om][p][j] + bo;
      }
    }
  }
}

extern "C" void kernel_launch(void* const* d_in, const int* in_sizes, int n_in,
                              void* d_out, int out_size, void* d_ws,
                              size_t ws_size, hipStream_t stream) {
  const float* x = (const float*)d_in[0];
  const float* wloc = (const float*)d_in[1];
  const float* wL = (const float*)d_in[2];
  const float* bloc = (const float*)d_in[3];
  const float* bro = (const float*)d_in[4];
  const float* eps_w = (const float*)d_in[5];
  const float* eps_b = (const float*)d_in[6];
  float* outp = (float*)d_out;

  short* wt = (short*)d_ws;                     // 9*2*64*32 bf16 = 73728 B
  float* bias = (float*)((char*)d_ws + 73728);  // 64 f32

  prep_kernel<<<16, 256, 0, stream>>>(wloc, wL, eps_w, bloc, bro, eps_b, wt,
                                      bias);
  conv_onepass_kernel<<<7168, 256, 0, stream>>>(x, wt, bias, outp);
}

// Round 6
// 362.437 us; speedup vs baseline: 3.4172x; 1.2704x over previous
//
#include <hip/hip_runtime.h>
#include <hip/hip_bf16.h>
#include <stdint.h>

typedef short bhalf8 __attribute__((ext_vector_type(8)));
typedef float facc4 __attribute__((ext_vector_type(4)));
typedef unsigned int uintv2 __attribute__((ext_vector_type(2)));

static __device__ __forceinline__ unsigned short f2bfu(float f) {
  return __builtin_bit_cast(unsigned short, __float2bfloat16(f));
}

// ---------------------------------------------------------------------------
// prep: sample conv weights w = loc + L@eps (L = tril(-1)+softplus(diag)*I)
// bf16 layout wt[a=kh*3+kw][kc=i>>5][o][i&31] (A-frag = contiguous 1KB/wave),
// bias = bias_loc + eps_b*softplus(bias_ro), 16-short zero pad for halo DMA.
// ---------------------------------------------------------------------------
__global__ void prep_kernel(const float* __restrict__ wloc,
                            const float* __restrict__ wL,
                            const float* __restrict__ eps_w,
                            const float* __restrict__ bloc,
                            const float* __restrict__ bro,
                            const float* __restrict__ eps_b,
                            short* __restrict__ wt, float* __restrict__ bias,
                            short* __restrict__ zeros) {
  int t = blockIdx.x * 256 + threadIdx.x;  // t = o*64 + i
  int o = t >> 6, i = t & 63;
  int kc = i >> 5, il = i & 31;
  const float* Lp = wL + (size_t)t * 81;
  const float* ep = eps_w + (size_t)t * 9;
  const float* lp = wloc + (size_t)t * 9;
  float e[9];
#pragma unroll
  for (int b = 0; b < 9; ++b) e[b] = ep[b];
#pragma unroll
  for (int a = 0; a < 9; ++a) {
    float s = lp[a];
    for (int b = 0; b < a; ++b) s += Lp[a * 9 + b] * e[b];
    float d = Lp[a * 9 + a];
    float sp = (d > 20.f) ? d : log1pf(expf(d));
    s += sp * e[a];
    wt[((a * 2 + kc) * 64 + o) * 32 + il] = (short)f2bfu(s);
  }
  if (t < 64) {
    float d = bro[t];
    float sp = (d > 20.f) ? d : log1pf(expf(d));
    bias[t] = bloc[t] + eps_b[t] * sp;
  }
  if (t < 16) zeros[t] = 0;
}

// ---------------------------------------------------------------------------
// pass 1: x NCHW f32 -> NHWC bf16 ([n][p=h*224+w][c64]). Pure streaming,
// no barriers -> measured ~5.4 TB/s in R2. Thread: 4 px x 8 ch.
// ---------------------------------------------------------------------------
__global__ __launch_bounds__(512) void to_nhwc_kernel(
    const float* __restrict__ x, short* __restrict__ xh) {
  int b = blockIdx.x;  // 32 n * 196 pixel-chunks of 256
  int n = b / 196;
  int p0 = (b % 196) * 256;
  int t = threadIdx.x;
  int pl = t >> 3, c8 = t & 7;
  const float* xp = x + (size_t)(n * 64 + c8 * 8) * 50176 + p0 + pl * 4;
  short* op = xh + ((size_t)n * 50176 + p0 + pl * 4) * 64 + c8 * 8;
  float4 v[8];
#pragma unroll
  for (int j = 0; j < 8; ++j) v[j] = *(const float4*)(xp + (size_t)j * 50176);
#pragma unroll
  for (int s = 0; s < 4; ++s) {
    bhalf8 h;
#pragma unroll
    for (int j = 0; j < 8; ++j) h[j] = f2bfu(((const float*)&v[j])[s]);
    *(bhalf8*)(op + s * 64) = h;
  }
}

// ---------------------------------------------------------------------------
// pass 2: 3x3 SAME conv from NHWC bf16. Block = 8 waves, 64o x 8r x 64px.
// Stage via global_load_lds width-16 (zero VALU, near-zero VGPR -> no spill;
// halo lanes DMA from zero pad). LDS layout [r:10][g:4][cc:66][8ch]
// (id = (r*4+g)*66+cc) -> B-frag ds_read_b128 is exactly 2 lanes/bank (free).
// Compute: 9 shifted K=32 GEMM steps; A-frags (1KB/wave) from global (L1-hot).
// launch_bounds(512,4): 128-reg budget = 64 AGPR acc + ~50 VGPR, fits.
// Block order: vertical neighbors consecutive + XCD chunking (halo L2 reuse).
// ---------------------------------------------------------------------------
__global__ __launch_bounds__(512, 4) void conv_nhwc_kernel(
    const short* __restrict__ xh, const short* __restrict__ wt,
    const float* __restrict__ bias, const short* __restrict__ zeros,
    float* __restrict__ out) {
  __shared__ short lds[10 * 4 * 66 * 8];  // 42240 B
  int b0 = blockIdx.x;
  int b = (b0 & 7) * 448 + (b0 >> 3);  // bijective: 3584 % 8 == 0
  int ht = b % 28;
  int rest = b / 28;
  int w4 = rest & 3, n = rest >> 2;
  int h0 = ht * 8, w0 = w4 * 64;
  int t = threadIdx.x, lane = t & 63, wv = t >> 6;
  int l15 = lane & 15, l4 = lane >> 4;

  facc4 acc[4][4];
#pragma unroll
  for (int om = 0; om < 4; ++om)
#pragma unroll
    for (int p = 0; p < 4; ++p) {
      facc4 z = {0.f, 0.f, 0.f, 0.f};
      acc[om][p] = z;
    }

  const size_t nbase = (size_t)n * 50176 * 64;
  for (int ic = 0; ic < 2; ++ic) {
    // ---- stage: 2640 16B chunks; id=(r*4+g)*66+cc; DMA direct to LDS ----
#pragma unroll
    for (int k = 0; k < 6; ++k) {
      int id = k * 512 + t;
      if (id < 2640) {
        int cc = id % 66;
        int rg = id / 66;
        int g = rg & 3, r = rg >> 2;
        int h_in = h0 - 1 + r, w_in = w0 - 1 + cc;
        const short* src =
            (h_in >= 0 && h_in < 224 && w_in >= 0 && w_in < 224)
                ? xh + nbase + (size_t)(h_in * 224 + w_in) * 64 + ic * 32 +
                      g * 8
                : zeros;
        __builtin_amdgcn_global_load_lds(
            (const __attribute__((address_space(1))) void*)src,
            (__attribute__((address_space(3))) void*)((char*)lds +
                                                      (k * 512 + wv * 64) * 16),
            16, 0, 0);
      }
    }
    __syncthreads();
    // ---- compute: 9 shifted positions, K=32 each ----
#pragma unroll
    for (int kh = 0; kh < 3; ++kh) {
      int r = wv + kh;  // input tile row for this wave's out row
#pragma unroll
      for (int kw = 0; kw < 3; ++kw) {
        const short* wb =
            wt + (((kh * 3 + kw) * 2 + ic) * 64 + l15) * 32 + (l4 << 3);
        bhalf8 a[4];
#pragma unroll
        for (int om = 0; om < 4; ++om)
          a[om] = *(const bhalf8*)(wb + om * 512);
#pragma unroll
        for (int p = 0; p < 4; ++p) {
          int tc = p * 16 + l15 + kw;
          bhalf8 bv =
              *(const bhalf8*)(lds + (((r * 4 + l4) * 66) + tc) * 8);
#pragma unroll
          for (int om = 0; om < 4; ++om)
            acc[om][p] = __builtin_amdgcn_mfma_f32_16x16x32_bf16(
                a[om], bv, acc[om][p], 0, 0, 0);
        }
      }
    }
    if (ic == 0) __syncthreads();
  }

  // ---- epilogue: D[o=om*16+l4*4+j][px=p*16+l15] + bias, NCHW f32 out ----
  int h = h0 + wv;
#pragma unroll
  for (int om = 0; om < 4; ++om) {
#pragma unroll
    for (int j = 0; j < 4; ++j) {
      int o = om * 16 + l4 * 4 + j;
      float bo = bias[o];
      float* op = out + ((size_t)(n * 64 + o) * 224 + h) * 224 + w0;
#pragma unroll
      for (int p = 0; p < 4; ++p) {
        int wg = w0 + p * 16 + l15;
        if (wg < 224) op[p * 16 + l15] = acc[om][p][j] + bo;
      }
    }
  }
}

// ---------------------------------------------------------------------------
// fallback (ws too small): R5 one-pass kernel (passed, 460 us).
// ---------------------------------------------------------------------------
#define LD1(cj, i)                                                   \
  ((hok && (w_in0 + (i)) >= 0 && (w_in0 + (i)) < 224)                \
       ? cbase[(size_t)(cj) * 50176 + w_in0 + (i)]                   \
       : 0.f)

__global__ __launch_bounds__(256, 4) void conv_onepass_kernel(
    const float* __restrict__ x, const short* __restrict__ wt,
    const float* __restrict__ bias, float* __restrict__ out) {
  __shared__ short lds[6 * 66 * 32];
  int b0 = blockIdx.x;
  int b = (b0 & 7) * 896 + (b0 >> 3);
  int ht = b % 56;
  int rest = b / 56;
  int w4 = rest & 3, n = rest >> 2;
  int h0 = ht * 4, w0 = w4 * 64;
  int t = threadIdx.x, lane = t & 63, wv = t >> 6;
  int l15 = lane & 15, l4 = lane >> 4;

  facc4 acc[4][4];
#pragma unroll
  for (int om = 0; om < 4; ++om)
#pragma unroll
    for (int p = 0; p < 4; ++p) {
      facc4 z = {0.f, 0.f, 0.f, 0.f};
      acc[om][p] = z;
    }

  for (int ic = 0; ic < 2; ++ic) {
#pragma unroll
    for (int k = 0; k < 4; ++k) {
      int u = t + k * 256;
      if (u < 816) {
        int chg = u & 7;
        int tmp = u >> 3;
        int ccg = tmp % 17, r = tmp / 17;
        int h_in = h0 - 1 + r;
        bool hok = (h_in >= 0) & (h_in < 224);
        int w_in0 = w0 - 1 + ccg * 4;
        int ch0 = ic * 32 + chg * 4;
        const float* cbase =
            x + ((size_t)(n * 64 + ch0) * 224 + (hok ? h_in : 0)) * 224;
        float4 v0, v1, v2, v3;
        if (hok && w_in0 >= 0 && w_in0 + 3 < 224) {
          v0 = *(const float4*)(cbase + w_in0);
          v1 = *(const float4*)(cbase + 50176 + w_in0);
          v2 = *(const float4*)(cbase + 2 * 50176 + w_in0);
          v3 = *(const float4*)(cbase + 3 * 50176 + w_in0);
        } else {
          v0 = make_float4(LD1(0, 0), LD1(0, 1), LD1(0, 2), LD1(0, 3));
          v1 = make_float4(LD1(1, 0), LD1(1, 1), LD1(1, 2), LD1(1, 3));
          v2 = make_float4(LD1(2, 0), LD1(2, 1), LD1(2, 2), LD1(2, 3));
          v3 = make_float4(LD1(3, 0), LD1(3, 1), LD1(3, 2), LD1(3, 3));
        }
        int g = chg >> 1;
        int halfsel = (chg & 1) << 2;
#pragma unroll
        for (int i = 0; i < 4; ++i) {
          int cc = ccg * 4 + i;
          if (cc < 66) {
            float a0 = ((const float*)&v0)[i], a1 = ((const float*)&v1)[i];
            float a2 = ((const float*)&v2)[i], a3 = ((const float*)&v3)[i];
            unsigned int w0p =
                (unsigned int)f2bfu(a0) | ((unsigned int)f2bfu(a1) << 16);
            unsigned int w1p =
                (unsigned int)f2bfu(a2) | ((unsigned int)f2bfu(a3) << 16);
            int addr =
                (r * 66 + cc) * 32 + ((g ^ ((cc >> 1) & 3)) << 3) + halfsel;
            uintv2 pk = {w0p, w1p};
            *(uintv2*)(lds + addr) = pk;
          }
        }
      }
    }
    __syncthreads();
#pragma unroll
    for (int kh = 0; kh < 3; ++kh) {
      int r = wv + kh;
#pragma unroll
      for (int kw = 0; kw < 3; ++kw) {
        const short* wb =
            wt + (((kh * 3 + kw) * 2 + ic) * 64 + l15) * 32 + (l4 << 3);
        bhalf8 a[4];
#pragma unroll
        for (int om = 0; om < 4; ++om)
          a[om] = *(const bhalf8*)(wb + om * 512);
#pragma unroll
        for (int p = 0; p < 4; ++p) {
          int tc = p * 16 + l15 + kw;
          bhalf8 bv = *(const bhalf8*)(lds + (r * 66 + tc) * 32 +
                                       ((l4 ^ ((tc >> 1) & 3)) << 3));
#pragma unroll
          for (int om = 0; om < 4; ++om)
            acc[om][p] = __builtin_amdgcn_mfma_f32_16x16x32_bf16(
                a[om], bv, acc[om][p], 0, 0, 0);
        }
      }
    }
    if (ic == 0) __syncthreads();
  }

  int h = h0 + wv;
#pragma unroll
  for (int om = 0; om < 4; ++om) {
#pragma unroll
    for (int j = 0; j < 4; ++j) {
      int o = om * 16 + l4 * 4 + j;
      float bo = bias[o];
      float* op = out + ((size_t)(n * 64 + o) * 224 + h) * 224 + w0;
#pragma unroll
      for (int p = 0; p < 4; ++p) {
        int wg = w0 + p * 16 + l15;
        if (wg < 224) op[p * 16 + l15] = acc[om][p][j] + bo;
      }
    }
  }
}

extern "C" void kernel_launch(void* const* d_in, const int* in_sizes, int n_in,
                              void* d_out, int out_size, void* d_ws,
                              size_t ws_size, hipStream_t stream) {
  const float* x = (const float*)d_in[0];
  const float* wloc = (const float*)d_in[1];
  const float* wL = (const float*)d_in[2];
  const float* bloc = (const float*)d_in[3];
  const float* bro = (const float*)d_in[4];
  const float* eps_w = (const float*)d_in[5];
  const float* eps_b = (const float*)d_in[6];
  float* outp = (float*)d_out;

  short* wt = (short*)d_ws;                      // 9*2*64*32 bf16 = 73728 B
  float* bias = (float*)((char*)d_ws + 73728);   // 64 f32
  short* zeros = (short*)((char*)d_ws + 73984);  // 16 bf16 zero pad
  short* xh = (short*)((char*)d_ws + 74240);     // 32*50176*64 bf16 = 205.5 MB
  const size_t need = 74240ull + (size_t)32 * 50176 * 64 * 2;

  prep_kernel<<<16, 256, 0, stream>>>(wloc, wL, eps_w, bloc, bro, eps_b, wt,
                                      bias, zeros);
  if (ws_size >= need) {
    to_nhwc_kernel<<<32 * 196, 512, 0, stream>>>(x, xh);
    conv_nhwc_kernel<<<3584, 512, 0, stream>>>(xh, wt, bias, zeros, outp);
  } else {
    conv_onepass_kernel<<<7168, 256, 0, stream>>>(x, wt, bias, outp);
  }
}